// Round 8
// baseline (170.653 us; speedup 1.0000x reference)
//
#include <hip/hip_runtime.h>
#include <math.h>

#define N_NODES 100000
#define N_EDGES 1600000
#define IN_DIM 128
#define OUT_DIM 64

// ---- coarse bucketing geometry ----
#define BSHIFT 7
#define BSIZE  (1 << BSHIFT)                       // 128 dst per bucket
#define NB     ((N_NODES + BSIZE - 1) >> BSHIFT)   // 782 buckets
#define EDGES_PER_BLK 4096
#define NBLK   ((N_EDGES + EDGES_PER_BLK - 1) / EDGES_PER_BLK)   // 391
#define SCANA_LEN (NB * NBLK)                      // 305762
#define SCANA_ITEMS 1024
#define SCANA_NB ((SCANA_LEN + SCANA_ITEMS - 1) / SCANA_ITEMS)   // 299
#define REC_CAP 3072                               // LDS records/bucket (E[cnt]=2046, sigma~45)

typedef short short8 __attribute__((ext_vector_type(8)));
typedef float f32x4 __attribute__((ext_vector_type(4)));
typedef float f32x2 __attribute__((ext_vector_type(2)));

__device__ __forceinline__ unsigned short f2bf(float x) {
    unsigned int u = __float_as_uint(x);
    return (unsigned short)((u + 0x7FFFu + ((u >> 16) & 1u)) >> 16);
}
__device__ __forceinline__ short8 pack_bf16x8(float4 p, float4 q) {
    short8 r;
    r[0] = (short)f2bf(p.x); r[1] = (short)f2bf(p.y);
    r[2] = (short)f2bf(p.z); r[3] = (short)f2bf(p.w);
    r[4] = (short)f2bf(q.x); r[5] = (short)f2bf(q.y);
    r[6] = (short)f2bf(q.z); r[7] = (short)f2bf(q.w);
    return r;
}
// d = a*b + d (packed 2x f32, dual-rate fp32 path)
__device__ __forceinline__ void pk_fma(f32x2& d, f32x2 a, f32x2 b) {
    asm("v_pk_fma_f32 %0, %1, %2, %0" : "+v"(d) : "v"(a), "v"(b));
}

// K1: per-(block,bucket) histogram (int4-vectorized dst loads). Block 0 also
// computes w1 = W^T a1, w2 = W^T a2 (fp32-exact associativity for s1/s2).
__global__ __launch_bounds__(256) void k_histA(const int* __restrict__ dst,
                                               int* __restrict__ hist_t,
                                               const float* __restrict__ W,
                                               const float* __restrict__ a_w,
                                               float* __restrict__ w1,
                                               float* __restrict__ w2) {
    __shared__ int lhist[NB];
    const int tid = threadIdx.x;
    const int blk = blockIdx.x;
    if (blk == 0 && tid < IN_DIM) {
        float r1 = 0.f, r2 = 0.f;
        #pragma unroll 8
        for (int dd = 0; dd < OUT_DIM; ++dd) {
            float wv = W[dd * IN_DIM + tid];
            r1 = fmaf(a_w[dd], wv, r1);
            r2 = fmaf(a_w[OUT_DIM + dd], wv, r2);
        }
        w1[tid] = r1; w2[tid] = r2;
    }
    for (int i = tid; i < NB; i += 256) lhist[i] = 0;
    __syncthreads();
    const int e0 = blk * EDGES_PER_BLK;
    #pragma unroll
    for (int j = 0; j < 4; ++j) {
        int e = e0 + (j * 256 + tid) * 4;
        if (e >= N_EDGES) continue;
        int4 d4 = *(const int4*)(dst + e);
        atomicAdd(&lhist[d4.x >> BSHIFT], 1);
        atomicAdd(&lhist[d4.y >> BSHIFT], 1);
        atomicAdd(&lhist[d4.z >> BSHIFT], 1);
        atomicAdd(&lhist[d4.w >> BSHIFT], 1);
    }
    __syncthreads();
    for (int i = tid; i < NB; i += 256) hist_t[i * NBLK + blk] = lhist[i];
}

// K2: Wh16 = bf16(h @ W.T) via MFMA 16x16x32_bf16; fp32 s1/s2 fused. No LDS.
__global__ __launch_bounds__(256) void k_wh(const float* __restrict__ h,
                                            const float* __restrict__ W,
                                            const float* __restrict__ w1,
                                            const float* __restrict__ w2,
                                            unsigned short* __restrict__ Wh16,
                                            float* __restrict__ s1,
                                            float* __restrict__ s2) {
    const int tid = threadIdx.x;
    const int wv = tid >> 6;
    const int l  = tid & 63;
    const int g  = l >> 4;
    const int lm = l & 15;
    const int node0 = blockIdx.x * 64 + wv * 16;
    const int row = node0 + lm;
    const int rowc = (row < N_NODES) ? row : (N_NODES - 1);
    const float* hrow = h + (size_t)rowc * IN_DIM;

    short8 afrag[4];
    float sp1 = 0.f, sp2 = 0.f;
    #pragma unroll
    for (int kt = 0; kt < 4; ++kt) {
        const int k0 = kt * 32 + g * 8;
        float4 p = *(const float4*)(hrow + k0);
        float4 q = *(const float4*)(hrow + k0 + 4);
        float4 u1 = *(const float4*)(w1 + k0);
        float4 v1 = *(const float4*)(w1 + k0 + 4);
        float4 u2 = *(const float4*)(w2 + k0);
        float4 v2 = *(const float4*)(w2 + k0 + 4);
        sp1 += p.x*u1.x + p.y*u1.y + p.z*u1.z + p.w*u1.w
             + q.x*v1.x + q.y*v1.y + q.z*v1.z + q.w*v1.w;
        sp2 += p.x*u2.x + p.y*u2.y + p.z*u2.z + p.w*u2.w
             + q.x*v2.x + q.y*v2.y + q.z*v2.z + q.w*v2.w;
        afrag[kt] = pack_bf16x8(p, q);
    }
    sp1 += __shfl_xor(sp1, 16, 64); sp1 += __shfl_xor(sp1, 32, 64);
    sp2 += __shfl_xor(sp2, 16, 64); sp2 += __shfl_xor(sp2, 32, 64);
    if (l < 16 && row < N_NODES) { s1[row] = sp1; s2[row] = sp2; }

    f32x4 acc[4] = {f32x4{0,0,0,0}, f32x4{0,0,0,0}, f32x4{0,0,0,0}, f32x4{0,0,0,0}};
    #pragma unroll
    for (int nt = 0; nt < 4; ++nt) {
        #pragma unroll
        for (int kt = 0; kt < 4; ++kt) {
            const float* wr = W + (size_t)(nt * 16 + lm) * IN_DIM + kt * 32 + g * 8;
            float4 p = *(const float4*)wr;
            float4 q = *(const float4*)(wr + 4);
            short8 bfrag = pack_bf16x8(p, q);
            acc[nt] = __builtin_amdgcn_mfma_f32_16x16x32_bf16(afrag[kt], bfrag, acc[nt], 0, 0, 0);
        }
    }
    #pragma unroll
    for (int nt = 0; nt < 4; ++nt) {
        #pragma unroll
        for (int r = 0; r < 4; ++r) {
            int nodo = node0 + g * 4 + r;
            if (nodo < N_NODES)
                Wh16[(size_t)nodo * OUT_DIM + nt * 16 + lm] = f2bf(acc[nt][r]);
        }
    }
}

// K3a/b/c: 3-phase exclusive scan of hist_t -> flat_scan.
__global__ __launch_bounds__(256) void k_scanA_part(const int* __restrict__ in,
                                                    int* __restrict__ bsum) {
    __shared__ int wsum[4];
    const int tid = threadIdx.x;
    const int base = blockIdx.x * SCANA_ITEMS + tid * 4;
    int s = 0;
    #pragma unroll
    for (int j = 0; j < 4; ++j) {
        int i = base + j;
        if (i < SCANA_LEN) s += in[i];
    }
    #pragma unroll
    for (int off = 32; off > 0; off >>= 1) s += __shfl_xor(s, off, 64);
    if ((tid & 63) == 0) wsum[tid >> 6] = s;
    __syncthreads();
    if (tid == 0) bsum[blockIdx.x] = wsum[0] + wsum[1] + wsum[2] + wsum[3];
}

// Parallel Hillis-Steele exclusive scan of the SCANA_NB (=299) block sums.
__global__ __launch_bounds__(512) void k_scanA_mid(int* __restrict__ bsum) {
    __shared__ int s[512];
    const int tid = threadIdx.x;
    s[tid] = (tid < SCANA_NB) ? bsum[tid] : 0;
    __syncthreads();
    #pragma unroll
    for (int off = 1; off < 512; off <<= 1) {
        int u = (tid >= off) ? s[tid - off] : 0;
        __syncthreads();
        s[tid] += u;
        __syncthreads();
    }
    if (tid < SCANA_NB) bsum[tid] = (tid > 0) ? s[tid - 1] : 0;
}

__global__ __launch_bounds__(256) void k_scanA_final(const int* __restrict__ in,
                                                     const int* __restrict__ bsum,
                                                     int* __restrict__ outscan) {
    __shared__ int wtot[4];
    const int tid = threadIdx.x;
    const int lane = tid & 63;
    const int wid = tid >> 6;
    const int base = blockIdx.x * SCANA_ITEMS + tid * 4;
    int c[4];
    #pragma unroll
    for (int j = 0; j < 4; ++j)
        c[j] = (base + j < SCANA_LEN) ? in[base + j] : 0;
    int tot = c[0] + c[1] + c[2] + c[3];
    int inc = tot;
    #pragma unroll
    for (int off = 1; off < 64; off <<= 1) {
        int u = __shfl_up(inc, off, 64);
        if (lane >= off) inc += u;
    }
    if (lane == 63) wtot[wid] = inc;
    __syncthreads();
    int wbase = 0;
    #pragma unroll
    for (int w = 0; w < 4; ++w) wbase += (w < wid) ? wtot[w] : 0;
    int run = bsum[blockIdx.x] + wbase + (inc - tot);
    #pragma unroll
    for (int j = 0; j < 4; ++j) {
        int i = base + j;
        if (i < SCANA_LEN) { outscan[i] = run; run += c[j]; }
    }
}

// K4: per-edge ae + coarse binning into block-private bucket ranges.
// Record: word0 = src | (dstlocal << 17)  (src < 2^17, dstlocal < 128).
__global__ __launch_bounds__(256) void k_binA(const int* __restrict__ ei,
                                              const float* __restrict__ s1,
                                              const float* __restrict__ s2,
                                              const int* __restrict__ flat_scan,
                                              int2* __restrict__ brec,
                                              float* __restrict__ ae_orig) {
    __shared__ int lbase[NB];
    __shared__ int lcur[NB];
    const int tid = threadIdx.x;
    const int blk = blockIdx.x;
    for (int i = tid; i < NB; i += 256) { lbase[i] = flat_scan[i * NBLK + blk]; lcur[i] = 0; }
    __syncthreads();
    const int e0 = blk * EDGES_PER_BLK;
    #pragma unroll
    for (int j = 0; j < 4; ++j) {
        int e = e0 + (j * 256 + tid) * 4;
        if (e >= N_EDGES) continue;
        int4 s4 = *(const int4*)(ei + e);
        int4 d4 = *(const int4*)(ei + N_EDGES + e);
        float4 aev;
        #pragma unroll
        for (int q = 0; q < 4; ++q) {
            int src = ((const int*)&s4)[q];
            int dst = ((const int*)&d4)[q];
            float a = s1[src] + s2[dst];
            a = (a > 0.f) ? a : 0.2f * a;            // leaky_relu(0.2)
            float ae = expf(a);                       // global-max shift cancels
            ((float*)&aev)[q] = ae;
            int b = dst >> BSHIFT;
            int r = atomicAdd(&lcur[b], 1);           // LDS atomic
            brec[lbase[b] + r] = make_int2(src | ((dst & (BSIZE - 1)) << 17),
                                           __float_as_int(ae));
        }
        *(float4*)(ae_orig + e) = aev;
    }
}

// K5 (fused fine-sort + aggregate): one block per 128-dst bucket.
// Phase 1: LDS hist + wave-scan + scatter bucket records into LDS (sorted).
// Phase 2: 4 waves x 32 nodes; 8 lanes/edge register segment-reduce reading
// pairs from LDS, bf16 Wh row gathers, v_pk_fma inner, ELU fused. No global
// sorted array, no offsets array.
__global__ __launch_bounds__(256) void k_fineagg(const int2* __restrict__ brec,
                                                 const int* __restrict__ flat_scan,
                                                 const unsigned short* __restrict__ Wh16,
                                                 float* __restrict__ out,
                                                 float* __restrict__ inv_tab) {
    __shared__ int2 lsorted[REC_CAP];
    __shared__ int lhist[BSIZE];
    __shared__ int lofs[BSIZE + 1];
    __shared__ int lcur[BSIZE];
    __shared__ float linv[BSIZE];
    const int tid = threadIdx.x;
    const int lane = tid & 63;
    const int wid = tid >> 6;
    const int b = blockIdx.x;
    const int base = flat_scan[b * NBLK];
    const int endp = (b + 1 < NB) ? flat_scan[(b + 1) * NBLK] : N_EDGES;
    const int cnt = endp - base;
    if (tid < BSIZE) lhist[tid] = 0;
    __syncthreads();
    // pass 1: histogram from global brec
    for (int i = tid; i < cnt; i += 256)
        atomicAdd(&lhist[(unsigned)brec[base + i].x >> 17], 1);
    __syncthreads();
    // wave-0 exclusive scan over 128 bins (2 bins/lane)
    if (wid == 0) {
        int c0 = lhist[2 * lane], c1 = lhist[2 * lane + 1];
        int s = c0 + c1;
        int inc = s;
        #pragma unroll
        for (int off = 1; off < 64; off <<= 1) {
            int u = __shfl_up(inc, off, 64);
            if (lane >= off) inc += u;
        }
        int ex = inc - s;
        lofs[2 * lane] = ex; lofs[2 * lane + 1] = ex + c0;
        lcur[2 * lane] = ex; lcur[2 * lane + 1] = ex + c0;
        if (lane == 63) lofs[BSIZE] = inc;
    }
    __syncthreads();
    // pass 2: scatter global brec -> LDS sorted positions (strip dstl)
    for (int i = tid; i < cnt; i += 256) {
        int2 rec = brec[base + i];
        int dstl = (unsigned)rec.x >> 17;
        int pos = atomicAdd(&lcur[dstl], 1);
        lsorted[pos] = make_int2(rec.x & 0x1FFFF, rec.y);
    }
    __syncthreads();
    // phase 2: segment reduce, 32 nodes per wave
    const int g = lane >> 3;       // edge slot 0..7
    const int o = lane & 7;        // dim octet 0..7
    const int dst0 = b << BSHIFT;
    for (int j = 0; j < 32; ++j) {
        const int bin = wid * 32 + j;
        const int node = dst0 + bin;
        if (node >= N_NODES) break;
        const int beg = lofs[bin];
        const int end2 = lofs[bin + 1];
        f32x2 acc2[4] = {f32x2{0,0}, f32x2{0,0}, f32x2{0,0}, f32x2{0,0}};
        float S = 0.f;
        int i = beg;
        for (; i + 16 <= end2; i += 16) {
            int2 pA = lsorted[i + g];
            int2 pB = lsorted[i + 8 + g];
            const int4 rA = *(const int4*)(Wh16 + ((size_t)pA.x << 6) + (o << 3));
            const int4 rB = *(const int4*)(Wh16 + ((size_t)pB.x << 6) + (o << 3));
            float aeA = __int_as_float(pA.y);
            float aeB = __int_as_float(pB.y);
            S += aeA + aeB;
            f32x2 a2A = {aeA, aeA}, a2B = {aeB, aeB};
            #pragma unroll
            for (int q = 0; q < 4; ++q) {
                int v = ((const int*)&rA)[q];
                f32x2 f = { __uint_as_float((unsigned)v << 16),
                            __uint_as_float((unsigned)v & 0xFFFF0000u) };
                pk_fma(acc2[q], f, a2A);
            }
            #pragma unroll
            for (int q = 0; q < 4; ++q) {
                int v = ((const int*)&rB)[q];
                f32x2 f = { __uint_as_float((unsigned)v << 16),
                            __uint_as_float((unsigned)v & 0xFFFF0000u) };
                pk_fma(acc2[q], f, a2B);
            }
        }
        for (; i < end2; i += 8) {
            int idx = i + g;
            int2 p = (idx < end2) ? lsorted[idx] : make_int2(0, 0);
            const int4 r = *(const int4*)(Wh16 + ((size_t)p.x << 6) + (o << 3));
            float ae = __int_as_float(p.y);          // 0 for masked lanes
            S += ae;
            f32x2 a2 = {ae, ae};
            #pragma unroll
            for (int q = 0; q < 4; ++q) {
                int v = ((const int*)&r)[q];
                f32x2 f = { __uint_as_float((unsigned)v << 16),
                            __uint_as_float((unsigned)v & 0xFFFF0000u) };
                pk_fma(acc2[q], f, a2);
            }
        }
        // fold the 8 edge slots (xor over lane bits 3,4,5)
        #pragma unroll
        for (int m = 8; m <= 32; m <<= 1) {
            S += __shfl_xor(S, m, 64);
            #pragma unroll
            for (int q = 0; q < 4; ++q) {
                acc2[q].x += __shfl_xor(acc2[q].x, m, 64);
                acc2[q].y += __shfl_xor(acc2[q].y, m, 64);
            }
        }
        const float inv = 1.f / (S + 1e-9f);
        if (lane == 0) linv[bin] = inv;
        if (g == 0) {                               // lanes 0..7 write 32B each
            float e[8];
            #pragma unroll
            for (int q = 0; q < 4; ++q) {
                float x0 = acc2[q].x * inv;
                float x1 = acc2[q].y * inv;
                e[2*q]   = (x0 > 0.f) ? x0 : expf(x0) - 1.f;
                e[2*q+1] = (x1 > 0.f) ? x1 : expf(x1) - 1.f;
            }
            float* orow = out + (size_t)node * OUT_DIM + o * 8;
            *(float4*)orow = make_float4(e[0], e[1], e[2], e[3]);
            *(float4*)(orow + 4) = make_float4(e[4], e[5], e[6], e[7]);
        }
    }
    __syncthreads();
    if (tid < BSIZE) {
        int node = dst0 + tid;
        if (node < N_NODES) inv_tab[node] = linv[tid];
    }
}

// K6: alpha_norm in original edge order, x4 vectorized.
__global__ __launch_bounds__(256) void k_norm(const int* __restrict__ dst_arr,
                                              const float* __restrict__ ae_orig,
                                              const float* __restrict__ inv_tab,
                                              float* __restrict__ alpha_norm) {
    int t = blockIdx.x * 256 + threadIdx.x;
    if (t >= N_EDGES / 4) return;
    int4 d4 = ((const int4*)dst_arr)[t];
    float4 a4 = ((const float4*)ae_orig)[t];
    float4 r;
    r.x = a4.x * inv_tab[d4.x];
    r.y = a4.y * inv_tab[d4.y];
    r.z = a4.z * inv_tab[d4.z];
    r.w = a4.w * inv_tab[d4.w];
    ((float4*)alpha_norm)[t] = r;
}

extern "C" void kernel_launch(void* const* d_in, const int* in_sizes, int n_in,
                              void* d_out, int out_size, void* d_ws, size_t ws_size,
                              hipStream_t stream) {
    const float* h   = (const float*)d_in[0];
    const float* W   = (const float*)d_in[1];
    const float* a_w = (const float*)d_in[2];
    const int*   ei  = (const int*)d_in[3];    // [2, E]: row0=src, row1=dst

    float* out        = (float*)d_out;                       // [N, 64] elu(out)
    float* alpha_norm = out + (size_t)N_NODES * OUT_DIM;     // [E]

    // workspace layout (~36 MB); 16B-aligned arrays first
    char* ws = (char*)d_ws;
    int2* brec      = (int2*)ws;            ws += (size_t)N_EDGES * 8;
    unsigned short* Wh16 = (unsigned short*)ws;  ws += (size_t)N_NODES * OUT_DIM * 2;
    float* ae_orig  = (float*)ws;           ws += (size_t)N_EDGES * 4;
    float* s1       = (float*)ws;           ws += (size_t)N_NODES * 4;
    float* s2       = (float*)ws;           ws += (size_t)N_NODES * 4;
    int*   hist_t   = (int*)ws;             ws += (size_t)SCANA_LEN * 4;
    int*   flat_scan= (int*)ws;             ws += (size_t)SCANA_LEN * 4;
    int*   bsum     = (int*)ws;             ws += (size_t)SCANA_NB * 4;
    float* inv_tab  = (float*)ws;           ws += (size_t)N_NODES * 4;
    float* w1       = (float*)ws;           ws += (size_t)IN_DIM * 4;
    float* w2       = (float*)ws;           ws += (size_t)IN_DIM * 4;

    k_histA<<<NBLK, 256, 0, stream>>>(ei + N_EDGES, hist_t, W, a_w, w1, w2);
    k_wh<<<(N_NODES + 63) / 64, 256, 0, stream>>>(h, W, w1, w2, Wh16, s1, s2);
    k_scanA_part<<<SCANA_NB, 256, 0, stream>>>(hist_t, bsum);
    k_scanA_mid<<<1, 512, 0, stream>>>(bsum);
    k_scanA_final<<<SCANA_NB, 256, 0, stream>>>(hist_t, bsum, flat_scan);
    k_binA<<<NBLK, 256, 0, stream>>>(ei, s1, s2, flat_scan, brec, ae_orig);
    k_fineagg<<<NB, 256, 0, stream>>>(brec, flat_scan, Wh16, out, inv_tab);
    k_norm<<<(N_EDGES / 4 + 255) / 256, 256, 0, stream>>>(ei + N_EDGES, ae_orig,
                                                          inv_tab, alpha_norm);
}

// Round 9
// 165.169 us; speedup vs baseline: 1.0332x; 1.0332x over previous
//
#include <hip/hip_runtime.h>
#include <math.h>

#define N_NODES 100000
#define N_EDGES 1600000
#define IN_DIM 128
#define OUT_DIM 64

// ---- coarse bucketing geometry ----
#define BSHIFT 9
#define BSIZE  (1 << BSHIFT)                       // 512 dst per bucket
#define NB     ((N_NODES + BSIZE - 1) >> BSHIFT)   // 196 buckets
#define EDGES_PER_BLK 4096
#define NBLK   ((N_EDGES + EDGES_PER_BLK - 1) / EDGES_PER_BLK)   // 391
#define SCANA_LEN (NB * NBLK)                      // 76636
#define SCANA_ITEMS 1024
#define SCANA_NB ((SCANA_LEN + SCANA_ITEMS - 1) / SCANA_ITEMS)   // 75

typedef short short8 __attribute__((ext_vector_type(8)));
typedef float f32x4 __attribute__((ext_vector_type(4)));
typedef float f32x2 __attribute__((ext_vector_type(2)));

__device__ __forceinline__ unsigned short f2bf(float x) {
    unsigned int u = __float_as_uint(x);
    return (unsigned short)((u + 0x7FFFu + ((u >> 16) & 1u)) >> 16);
}
__device__ __forceinline__ short8 pack_bf16x8(float4 p, float4 q) {
    short8 r;
    r[0] = (short)f2bf(p.x); r[1] = (short)f2bf(p.y);
    r[2] = (short)f2bf(p.z); r[3] = (short)f2bf(p.w);
    r[4] = (short)f2bf(q.x); r[5] = (short)f2bf(q.y);
    r[6] = (short)f2bf(q.z); r[7] = (short)f2bf(q.w);
    return r;
}
// d += a*b (packed 2x f32, dual-rate fp32 path; validated r8)
__device__ __forceinline__ void pk_fma(f32x2& d, f32x2 a, f32x2 b) {
    asm("v_pk_fma_f32 %0, %1, %2, %0" : "+v"(d) : "v"(a), "v"(b));
}

// K1: per-(block,bucket) histogram (int4 dst loads). Block 0 also computes
// w1 = W^T a1, w2 = W^T a2 (fp32-exact associativity for s1/s2).
__global__ __launch_bounds__(256) void k_histA(const int* __restrict__ dst,
                                               int* __restrict__ hist_t,
                                               const float* __restrict__ W,
                                               const float* __restrict__ a_w,
                                               float* __restrict__ w1,
                                               float* __restrict__ w2) {
    __shared__ int lhist[NB];
    const int tid = threadIdx.x;
    const int blk = blockIdx.x;
    if (blk == 0 && tid < IN_DIM) {
        float r1 = 0.f, r2 = 0.f;
        #pragma unroll 8
        for (int dd = 0; dd < OUT_DIM; ++dd) {
            float wv = W[dd * IN_DIM + tid];
            r1 = fmaf(a_w[dd], wv, r1);
            r2 = fmaf(a_w[OUT_DIM + dd], wv, r2);
        }
        w1[tid] = r1; w2[tid] = r2;
    }
    if (tid < NB) lhist[tid] = 0;
    __syncthreads();
    const int e0 = blk * EDGES_PER_BLK;
    #pragma unroll
    for (int j = 0; j < 4; ++j) {
        int e = e0 + (j * 256 + tid) * 4;
        if (e >= N_EDGES) continue;
        int4 d4 = *(const int4*)(dst + e);
        atomicAdd(&lhist[d4.x >> BSHIFT], 1);
        atomicAdd(&lhist[d4.y >> BSHIFT], 1);
        atomicAdd(&lhist[d4.z >> BSHIFT], 1);
        atomicAdd(&lhist[d4.w >> BSHIFT], 1);
    }
    __syncthreads();
    if (tid < NB) hist_t[tid * NBLK + blk] = lhist[tid];
}

// K2: Wh16 = bf16(h @ W.T) via MFMA 16x16x32_bf16; fp32 s1/s2 fused. No LDS.
__global__ __launch_bounds__(256) void k_wh(const float* __restrict__ h,
                                            const float* __restrict__ W,
                                            const float* __restrict__ w1,
                                            const float* __restrict__ w2,
                                            unsigned short* __restrict__ Wh16,
                                            float* __restrict__ s1,
                                            float* __restrict__ s2) {
    const int tid = threadIdx.x;
    const int wv = tid >> 6;
    const int l  = tid & 63;
    const int g  = l >> 4;
    const int lm = l & 15;
    const int node0 = blockIdx.x * 64 + wv * 16;
    const int row = node0 + lm;
    const int rowc = (row < N_NODES) ? row : (N_NODES - 1);
    const float* hrow = h + (size_t)rowc * IN_DIM;

    short8 afrag[4];
    float sp1 = 0.f, sp2 = 0.f;
    #pragma unroll
    for (int kt = 0; kt < 4; ++kt) {
        const int k0 = kt * 32 + g * 8;
        float4 p = *(const float4*)(hrow + k0);
        float4 q = *(const float4*)(hrow + k0 + 4);
        float4 u1 = *(const float4*)(w1 + k0);
        float4 v1 = *(const float4*)(w1 + k0 + 4);
        float4 u2 = *(const float4*)(w2 + k0);
        float4 v2 = *(const float4*)(w2 + k0 + 4);
        sp1 += p.x*u1.x + p.y*u1.y + p.z*u1.z + p.w*u1.w
             + q.x*v1.x + q.y*v1.y + q.z*v1.z + q.w*v1.w;
        sp2 += p.x*u2.x + p.y*u2.y + p.z*u2.z + p.w*u2.w
             + q.x*v2.x + q.y*v2.y + q.z*v2.z + q.w*v2.w;
        afrag[kt] = pack_bf16x8(p, q);
    }
    sp1 += __shfl_xor(sp1, 16, 64); sp1 += __shfl_xor(sp1, 32, 64);
    sp2 += __shfl_xor(sp2, 16, 64); sp2 += __shfl_xor(sp2, 32, 64);
    if (l < 16 && row < N_NODES) { s1[row] = sp1; s2[row] = sp2; }

    f32x4 acc[4] = {f32x4{0,0,0,0}, f32x4{0,0,0,0}, f32x4{0,0,0,0}, f32x4{0,0,0,0}};
    #pragma unroll
    for (int nt = 0; nt < 4; ++nt) {
        #pragma unroll
        for (int kt = 0; kt < 4; ++kt) {
            const float* wr = W + (size_t)(nt * 16 + lm) * IN_DIM + kt * 32 + g * 8;
            float4 p = *(const float4*)wr;
            float4 q = *(const float4*)(wr + 4);
            short8 bfrag = pack_bf16x8(p, q);
            acc[nt] = __builtin_amdgcn_mfma_f32_16x16x32_bf16(afrag[kt], bfrag, acc[nt], 0, 0, 0);
        }
    }
    #pragma unroll
    for (int nt = 0; nt < 4; ++nt) {
        #pragma unroll
        for (int r = 0; r < 4; ++r) {
            int nodo = node0 + g * 4 + r;
            if (nodo < N_NODES)
                Wh16[(size_t)nodo * OUT_DIM + nt * 16 + lm] = f2bf(acc[nt][r]);
        }
    }
}

// K3a/b/c: 3-phase exclusive scan of hist_t -> flat_scan.
__global__ __launch_bounds__(256) void k_scanA_part(const int* __restrict__ in,
                                                    int* __restrict__ bsum) {
    __shared__ int wsum[4];
    const int tid = threadIdx.x;
    const int base = blockIdx.x * SCANA_ITEMS + tid * 4;
    int s = 0;
    #pragma unroll
    for (int j = 0; j < 4; ++j) {
        int i = base + j;
        if (i < SCANA_LEN) s += in[i];
    }
    #pragma unroll
    for (int off = 32; off > 0; off >>= 1) s += __shfl_xor(s, off, 64);
    if ((tid & 63) == 0) wsum[tid >> 6] = s;
    __syncthreads();
    if (tid == 0) bsum[blockIdx.x] = wsum[0] + wsum[1] + wsum[2] + wsum[3];
}

// Parallel Hillis-Steele exclusive scan of the SCANA_NB (=75) block sums.
__global__ __launch_bounds__(128) void k_scanA_mid(int* __restrict__ bsum) {
    __shared__ int s[128];
    const int tid = threadIdx.x;
    s[tid] = (tid < SCANA_NB) ? bsum[tid] : 0;
    __syncthreads();
    #pragma unroll
    for (int off = 1; off < 128; off <<= 1) {
        int u = (tid >= off) ? s[tid - off] : 0;
        __syncthreads();
        s[tid] += u;
        __syncthreads();
    }
    if (tid < SCANA_NB) bsum[tid] = (tid > 0) ? s[tid - 1] : 0;
}

__global__ __launch_bounds__(256) void k_scanA_final(const int* __restrict__ in,
                                                     const int* __restrict__ bsum,
                                                     int* __restrict__ outscan) {
    __shared__ int wtot[4];
    const int tid = threadIdx.x;
    const int lane = tid & 63;
    const int wid = tid >> 6;
    const int base = blockIdx.x * SCANA_ITEMS + tid * 4;
    int c[4];
    #pragma unroll
    for (int j = 0; j < 4; ++j)
        c[j] = (base + j < SCANA_LEN) ? in[base + j] : 0;
    int tot = c[0] + c[1] + c[2] + c[3];
    int inc = tot;
    #pragma unroll
    for (int off = 1; off < 64; off <<= 1) {
        int u = __shfl_up(inc, off, 64);
        if (lane >= off) inc += u;
    }
    if (lane == 63) wtot[wid] = inc;
    __syncthreads();
    int wbase = 0;
    #pragma unroll
    for (int w = 0; w < 4; ++w) wbase += (w < wid) ? wtot[w] : 0;
    int run = bsum[blockIdx.x] + wbase + (inc - tot);
    #pragma unroll
    for (int j = 0; j < 4; ++j) {
        int i = base + j;
        if (i < SCANA_LEN) { outscan[i] = run; run += c[j]; }
    }
}

// K4: per-edge ae + coarse binning into block-private bucket ranges.
// Record: word0 = src | (dstlocal << 17)  (src < 2^17, dstlocal < 512).
__global__ __launch_bounds__(256) void k_binA(const int* __restrict__ ei,
                                              const float* __restrict__ s1,
                                              const float* __restrict__ s2,
                                              const int* __restrict__ flat_scan,
                                              int2* __restrict__ brec,
                                              float* __restrict__ ae_orig) {
    __shared__ int lbase[NB];
    __shared__ int lcur[NB];
    const int tid = threadIdx.x;
    const int blk = blockIdx.x;
    if (tid < NB) { lbase[tid] = flat_scan[tid * NBLK + blk]; lcur[tid] = 0; }
    __syncthreads();
    const int e0 = blk * EDGES_PER_BLK;
    #pragma unroll
    for (int j = 0; j < 4; ++j) {
        int e = e0 + (j * 256 + tid) * 4;
        if (e >= N_EDGES) continue;
        int4 s4 = *(const int4*)(ei + e);
        int4 d4 = *(const int4*)(ei + N_EDGES + e);
        float4 aev;
        #pragma unroll
        for (int q = 0; q < 4; ++q) {
            int src = ((const int*)&s4)[q];
            int dst = ((const int*)&d4)[q];
            float a = s1[src] + s2[dst];
            a = (a > 0.f) ? a : 0.2f * a;            // leaky_relu(0.2)
            float ae = expf(a);                       // global-max shift cancels
            ((float*)&aev)[q] = ae;
            int b = dst >> BSHIFT;
            int r = atomicAdd(&lcur[b], 1);           // LDS atomic
            brec[lbase[b] + r] = make_int2(src | ((dst & (BSIZE - 1)) << 17),
                                           __float_as_int(ae));
        }
        *(float4*)(ae_orig + e) = aev;
    }
}

// K5: fine sort within each 512-dst bucket -> offsets[], dst-sorted (src,ae),
// AND per-dst denominator (LDS float atomics) -> inv_tab. One block/bucket.
__global__ __launch_bounds__(256) void k_fine(const int2* __restrict__ brec,
                                              const int* __restrict__ flat_scan,
                                              int* __restrict__ offsets,
                                              int2* __restrict__ sa_sorted,
                                              float* __restrict__ inv_tab) {
    __shared__ int lhist[BSIZE];
    __shared__ int lofs[BSIZE];
    __shared__ int lcur[BSIZE];
    __shared__ float lsum[BSIZE];
    __shared__ int wsum[4];
    const int tid = threadIdx.x;
    const int lane = tid & 63;
    const int wid = tid >> 6;
    const int b = blockIdx.x;
    const int base = flat_scan[b * NBLK];
    const int endp = (b + 1 < NB) ? flat_scan[(b + 1) * NBLK] : N_EDGES;
    const int cnt = endp - base;
    lhist[tid] = 0; lhist[tid + 256] = 0;
    lsum[tid] = 0.f; lsum[tid + 256] = 0.f;
    __syncthreads();
    for (int i = tid; i < cnt; i += 256)
        atomicAdd(&lhist[(unsigned)brec[base + i].x >> 17], 1);
    __syncthreads();
    int c0 = lhist[2 * tid], c1 = lhist[2 * tid + 1];
    int s = c0 + c1;
    int inc = s;
    #pragma unroll
    for (int off = 1; off < 64; off <<= 1) {
        int u = __shfl_up(inc, off, 64);
        if (lane >= off) inc += u;
    }
    if (lane == 63) wsum[wid] = inc;
    __syncthreads();
    int wb = 0;
    #pragma unroll
    for (int w = 0; w < 4; ++w) wb += (w < wid) ? wsum[w] : 0;
    int ex = wb + inc - s;
    lofs[2 * tid] = ex; lofs[2 * tid + 1] = ex + c0;
    lcur[2 * tid] = ex; lcur[2 * tid + 1] = ex + c0;
    __syncthreads();
    const int dst0 = b << BSHIFT;
    #pragma unroll
    for (int j = 0; j < 2; ++j) {
        int jj = tid + j * 256;
        int node = dst0 + jj;
        if (node < N_NODES) offsets[node] = base + lofs[jj];
    }
    if (b == NB - 1 && tid == 0) offsets[N_NODES] = N_EDGES;
    for (int i = tid; i < cnt; i += 256) {
        int2 rec = brec[base + i];
        int dstl = (unsigned)rec.x >> 17;
        float ae = __int_as_float(rec.y);
        int pos = base + atomicAdd(&lcur[dstl], 1);
        sa_sorted[pos] = make_int2(rec.x & 0x1FFFF, rec.y);
        atomicAdd(&lsum[dstl], ae);
    }
    __syncthreads();
    #pragma unroll
    for (int j = 0; j < 2; ++j) {
        int jj = tid + j * 256;
        int node = dst0 + jj;
        if (node < N_NODES) inv_tab[node] = 1.f / (lsum[jj] + 1e-9f);
    }
}

// K6: one wave per dst node. 8 lanes/edge (slot g=l>>3, octet o=l&7):
// per-lane pair load + dwordx4 (8 bf16 dims) row load, v_pk_fma inner,
// 16 edges in flight, shfl_xor(8,16,32) slot fold. inv from inv_tab
// (precomputed in k_fine -> no per-edge S accumulation). ELU fused.
__global__ __launch_bounds__(256) void k_agg(const int2* __restrict__ sa_sorted,
                                             const int* __restrict__ offsets,
                                             const unsigned short* __restrict__ Wh16,
                                             const float* __restrict__ inv_tab,
                                             float* __restrict__ out) {
    const int gid = blockIdx.x * 256 + threadIdx.x;
    const int node = gid >> 6;
    const int l = gid & 63;
    if (node >= N_NODES) return;
    const int g = l >> 3;       // edge slot 0..7
    const int o = l & 7;        // dim octet 0..7
    const int beg = offsets[node];
    const int end = offsets[node + 1];
    f32x2 acc2[4] = {f32x2{0,0}, f32x2{0,0}, f32x2{0,0}, f32x2{0,0}};
    int i = beg;
    for (; i + 16 <= end; i += 16) {
        int2 pA = sa_sorted[i + g];
        int2 pB = sa_sorted[i + 8 + g];
        const int4 rA = *(const int4*)(Wh16 + ((size_t)pA.x << 6) + (o << 3));
        const int4 rB = *(const int4*)(Wh16 + ((size_t)pB.x << 6) + (o << 3));
        float aeA = __int_as_float(pA.y);
        float aeB = __int_as_float(pB.y);
        f32x2 a2A = {aeA, aeA}, a2B = {aeB, aeB};
        #pragma unroll
        for (int q = 0; q < 4; ++q) {
            int v = ((const int*)&rA)[q];
            f32x2 f = { __uint_as_float((unsigned)v << 16),
                        __uint_as_float((unsigned)v & 0xFFFF0000u) };
            pk_fma(acc2[q], f, a2A);
        }
        #pragma unroll
        for (int q = 0; q < 4; ++q) {
            int v = ((const int*)&rB)[q];
            f32x2 f = { __uint_as_float((unsigned)v << 16),
                        __uint_as_float((unsigned)v & 0xFFFF0000u) };
            pk_fma(acc2[q], f, a2B);
        }
    }
    for (; i < end; i += 8) {
        int idx = i + g;
        int2 p = (idx < end) ? sa_sorted[idx] : make_int2(0, 0);
        const int4 r = *(const int4*)(Wh16 + ((size_t)p.x << 6) + (o << 3));
        float ae = __int_as_float(p.y);          // 0 for masked lanes
        f32x2 a2 = {ae, ae};
        #pragma unroll
        for (int q = 0; q < 4; ++q) {
            int v = ((const int*)&r)[q];
            f32x2 f = { __uint_as_float((unsigned)v << 16),
                        __uint_as_float((unsigned)v & 0xFFFF0000u) };
            pk_fma(acc2[q], f, a2);
        }
    }
    // fold the 8 edge slots (xor over lane bits 3,4,5)
    #pragma unroll
    for (int m = 8; m <= 32; m <<= 1) {
        #pragma unroll
        for (int q = 0; q < 4; ++q) {
            acc2[q].x += __shfl_xor(acc2[q].x, m, 64);
            acc2[q].y += __shfl_xor(acc2[q].y, m, 64);
        }
    }
    if (g == 0) {                               // lanes 0..7 write 32B each
        const float inv = inv_tab[node];
        float e[8];
        #pragma unroll
        for (int q = 0; q < 4; ++q) {
            float x0 = acc2[q].x * inv;
            float x1 = acc2[q].y * inv;
            e[2*q]   = (x0 > 0.f) ? x0 : expf(x0) - 1.f;
            e[2*q+1] = (x1 > 0.f) ? x1 : expf(x1) - 1.f;
        }
        float* orow = out + (size_t)node * OUT_DIM + o * 8;
        *(float4*)orow = make_float4(e[0], e[1], e[2], e[3]);
        *(float4*)(orow + 4) = make_float4(e[4], e[5], e[6], e[7]);
    }
}

// K7: alpha_norm in original edge order, x4 vectorized.
__global__ __launch_bounds__(256) void k_norm(const int* __restrict__ dst_arr,
                                              const float* __restrict__ ae_orig,
                                              const float* __restrict__ inv_tab,
                                              float* __restrict__ alpha_norm) {
    int t = blockIdx.x * 256 + threadIdx.x;
    if (t >= N_EDGES / 4) return;
    int4 d4 = ((const int4*)dst_arr)[t];
    float4 a4 = ((const float4*)ae_orig)[t];
    float4 r;
    r.x = a4.x * inv_tab[d4.x];
    r.y = a4.y * inv_tab[d4.y];
    r.z = a4.z * inv_tab[d4.z];
    r.w = a4.w * inv_tab[d4.w];
    ((float4*)alpha_norm)[t] = r;
}

extern "C" void kernel_launch(void* const* d_in, const int* in_sizes, int n_in,
                              void* d_out, int out_size, void* d_ws, size_t ws_size,
                              hipStream_t stream) {
    const float* h   = (const float*)d_in[0];
    const float* W   = (const float*)d_in[1];
    const float* a_w = (const float*)d_in[2];
    const int*   ei  = (const int*)d_in[3];    // [2, E]: row0=src, row1=dst

    float* out        = (float*)d_out;                       // [N, 64] elu(out)
    float* alpha_norm = out + (size_t)N_NODES * OUT_DIM;     // [E]

    // workspace layout (~46 MB); 16B-aligned arrays first
    char* ws = (char*)d_ws;
    int2* brec      = (int2*)ws;            ws += (size_t)N_EDGES * 8;
    int2* sa_sorted = (int2*)ws;            ws += (size_t)N_EDGES * 8;
    unsigned short* Wh16 = (unsigned short*)ws;  ws += (size_t)N_NODES * OUT_DIM * 2;
    float* ae_orig  = (float*)ws;           ws += (size_t)N_EDGES * 4;
    float* s1       = (float*)ws;           ws += (size_t)N_NODES * 4;
    float* s2       = (float*)ws;           ws += (size_t)N_NODES * 4;
    int*   hist_t   = (int*)ws;             ws += (size_t)SCANA_LEN * 4;
    int*   flat_scan= (int*)ws;             ws += (size_t)SCANA_LEN * 4;
    int*   bsum     = (int*)ws;             ws += (size_t)SCANA_NB * 4;
    int*   offsets  = (int*)ws;             ws += (size_t)(N_NODES + 1) * 4;
    float* inv_tab  = (float*)ws;           ws += (size_t)N_NODES * 4;
    float* w1       = (float*)ws;           ws += (size_t)IN_DIM * 4;
    float* w2       = (float*)ws;           ws += (size_t)IN_DIM * 4;

    k_histA<<<NBLK, 256, 0, stream>>>(ei + N_EDGES, hist_t, W, a_w, w1, w2);
    k_wh<<<(N_NODES + 63) / 64, 256, 0, stream>>>(h, W, w1, w2, Wh16, s1, s2);
    k_scanA_part<<<SCANA_NB, 256, 0, stream>>>(hist_t, bsum);
    k_scanA_mid<<<1, 128, 0, stream>>>(bsum);
    k_scanA_final<<<SCANA_NB, 256, 0, stream>>>(hist_t, bsum, flat_scan);
    k_binA<<<NBLK, 256, 0, stream>>>(ei, s1, s2, flat_scan, brec, ae_orig);
    k_fine<<<NB, 256, 0, stream>>>(brec, flat_scan, offsets, sa_sorted, inv_tab);
    k_agg<<<(N_NODES * 64 + 255) / 256, 256, 0, stream>>>(sa_sorted, offsets, Wh16,
                                                          inv_tab, out);
    k_norm<<<(N_EDGES / 4 + 255) / 256, 256, 0, stream>>>(ei + N_EDGES, ae_orig,
                                                          inv_tab, alpha_norm);
}